// Round 13
// baseline (162.459 us; speedup 1.0000x reference)
//
#include <hip/hip_runtime.h>

// RelationGAT fused flash-attention, MFMA fp16 (gfx950) -- R19 "R18 + non-temporal K/V loads".
// out = softmax((x@Wq^T+bq) @ (nb@Wk^T+bk)^T) @ nb @ Wv^T + bv
// bk cancels in softmax. Q~ = x@G + u, G = Wq^T Wk, u = bq^T Wk; K=V=raw nb.
//
// R19 theory: last surviving mechanism after 12 variants -- per-CU load-service
// cost in the vL1/TA path. Every K/V load = 16 cache lines, 256KB stream never
// L1-resident -> every line an L1 miss eating miss-handling slots. Explains:
// contiguity -14%, traffic x2 +19% (more misses), TLP@const-traffic +10%
// (miss-slot contention), prefetch-depth null (service rate not latency binds).
// Probe: __builtin_nontemporal_load (nt bit, skip L1 allocation) on all KF/VF
// loads; GF/x/Wv stay cached (reuse case). Zero numerics/structural risk.
// PRE-COMMIT: 72-76 null or >=78 regression => revert to R18 and stop.
//
// Workspace layout (278784 B):
//   [0,8192)         GFh  fp16 frag-major G^T hi: [f=mt*2+ks][lane][8]
//   [8192,16384)     GFl  fp16 frag-major G^T lo
//   [16384,16640)    uW   f32 [64]
//   [16640,147712)   KF   fp16 [tile][f=t*2+h][lane][8], key-permuted
//   [147712,278784)  VF   fp16 [tile][dt][lane][8], natural key order

#define N_ROWS 100000
#define LOG2E 1.44269504088896f
#define GATE_THR 11.5424f   // 8 nats in log2 units; p <= 2^11.54 ~ 2981 fits fp16

typedef __attribute__((ext_vector_type(8))) _Float16 half8;
typedef __attribute__((ext_vector_type(2))) __fp16   fp16x2;   // cvt_pkrtz return type
typedef __attribute__((ext_vector_type(4))) float    f32x4;

#define MFMA16(a,b,c) __builtin_amdgcn_mfma_f32_16x16x32_f16((a),(b),(c),0,0,0)

static __device__ __forceinline__ f32x4 zero4() {
    f32x4 v = {0.f, 0.f, 0.f, 0.f};
    return v;
}

// non-temporal 16B fragment load: nt bit -> no L1 allocation, stream from L2
static __device__ __forceinline__ half8 ntload8(const unsigned short* p) {
    return __builtin_nontemporal_load((const half8*)p);
}

// ---------------- prep: GF hi/lo + u (block 0), nb -> KF/VF fp16 (blocks 1..32) ----------------
__global__ __launch_bounds__(256)
void prep_kernel(const float* __restrict__ nb, const float* __restrict__ Wq,
                 const float* __restrict__ bq, const float* __restrict__ Wk,
                 unsigned short* __restrict__ GFh, unsigned short* __restrict__ GFl,
                 float* __restrict__ uW, unsigned short* __restrict__ KF,
                 unsigned short* __restrict__ VF)
{
    __shared__ __align__(16) float sm[8192];   // 32KB: blk0 Wk|Wq, blks>0 transpose tile
    const int tid = threadIdx.x;
    if (blockIdx.x == 0) {
        const float4* wk4 = (const float4*)Wk;
        const float4* wq4 = (const float4*)Wq;
        float4* dk = (float4*)sm;
        float4* dq = (float4*)(sm + 4096);
        #pragma unroll
        for (int u = 0; u < 4; u++) {
            dk[u * 256 + tid] = wk4[u * 256 + tid];
            dq[u * 256 + tid] = wq4[u * 256 + tid];
        }
        __syncthreads();
        const int e2 = tid & 63, e1g = (tid >> 6) * 16;
        float g[16];
        #pragma unroll
        for (int q = 0; q < 16; q++) g[q] = 0.f;
        for (int w = 0; w < 64; w++) {
            float kv = sm[w * 64 + e2];
            const float* wqp = sm + 4096 + w * 64 + e1g;
            #pragma unroll
            for (int q = 0; q < 16; q++) g[q] = fmaf(wqp[q], kv, g[q]);
        }
        union { half8 h; uint4 u; } ph0, pl0, ph1, pl1;
        #pragma unroll
        for (int i = 0; i < 8; i++) {
            _Float16 h0 = (_Float16)g[i];
            ph0.h[i] = h0; pl0.h[i] = (_Float16)(g[i] - (float)h0);
            _Float16 h1 = (_Float16)g[8 + i];
            ph1.h[i] = h1; pl1.h[i] = (_Float16)(g[8 + i] - (float)h1);
        }
        // frag-major: f = mt*2+ks, lane = Q*16+c ; this thread owns row e2 ->
        // (mt = e2>>4, c = e2&15), cols e1g..e1g+15 -> ks = tid>>7, Q0 = 2*((tid>>6)&1)
        const int mt = e2 >> 4, cc = e2 & 15;
        const int ks = tid >> 7, Q0 = 2 * ((tid >> 6) & 1);
        const int f  = mt * 2 + ks;
        *(uint4*)(GFh + (f * 64 + Q0 * 16 + cc) * 8)       = ph0.u;
        *(uint4*)(GFh + (f * 64 + (Q0 + 1) * 16 + cc) * 8) = ph1.u;
        *(uint4*)(GFl + (f * 64 + Q0 * 16 + cc) * 8)       = pl0.u;
        *(uint4*)(GFl + (f * 64 + (Q0 + 1) * 16 + cc) * 8) = pl1.u;
        if (tid < 64) {
            float uu = 0.f;
            for (int w = 0; w < 64; w++) uu = fmaf(bq[w], sm[w * 64 + tid], uu);
            uW[tid] = uu;
        }
    } else {
        const int T0 = blockIdx.x - 1;   // this block's 32-key tile
        const int j0 = T0 * 32;
        // stage 32x64 f32 tile to LDS [32][65] for the VF transpose
        {
            const int jr = tid >> 3, c0 = (tid & 7) * 8;
            const float* np = nb + (size_t)(j0 + jr) * 64 + c0;
            float4 v0 = *(const float4*)np;
            float4 v1 = *(const float4*)(np + 4);
            sm[jr * 65 + c0 + 0] = v0.x; sm[jr * 65 + c0 + 1] = v0.y;
            sm[jr * 65 + c0 + 2] = v0.z; sm[jr * 65 + c0 + 3] = v0.w;
            sm[jr * 65 + c0 + 4] = v1.x; sm[jr * 65 + c0 + 5] = v1.y;
            sm[jr * 65 + c0 + 6] = v1.z; sm[jr * 65 + c0 + 7] = v1.w;
        }
        // KF direct from global: tid -> (f=(t,h), lane=(Q,c)); stored key row is the
        // PERMUTED key keyof(t,c) so that S-frag reg r at lane(Q,c) = key 8Q+4t+r.
        {
            const int f = tid >> 6, ln = tid & 63;
            const int t = f >> 1, h = f & 1, Qw = ln >> 4, cw = ln & 15;
            const int key = ((cw >> 3) & 1) * 16 + ((cw >> 2) & 1) * 8 + 4 * t + (cw & 3);
            const float* kp = nb + (size_t)(j0 + key) * 64 + h * 32 + Qw * 8;
            float b[8];
            *(float4*)b       = *(const float4*)kp;
            *(float4*)(b + 4) = *(const float4*)(kp + 4);
            union { half8 hh; uint4 u; } pk;
            #pragma unroll
            for (int i = 0; i < 8; i++) pk.hh[i] = (_Float16)b[i];
            *(uint4*)(KF + (size_t)T0 * 2048 + f * 512 + ln * 8) = pk.u;
        }
        __syncthreads();
        // VF from LDS transpose: VF[T0][dt][lane(Q,c)][i] = nb[j0 + Q*8 + i][dt*16+c]
        {
            const int dt = tid >> 6, ln = tid & 63;
            const int Qw = ln >> 4, cw = ln & 15;
            union { half8 hh; uint4 u; } pv;
            #pragma unroll
            for (int i = 0; i < 8; i++)
                pv.hh[i] = (_Float16)sm[(Qw * 8 + i) * 65 + dt * 16 + cw];
            *(uint4*)(VF + (size_t)T0 * 2048 + dt * 512 + ln * 8) = pv.u;
        }
    }
}

// One 32-key flash step: compute with ck/vA, prefetch K[Tn] into nk, reload vA <- V[Tn]
// at the end (WAR after PV issue; ~3/4-step slack). MFMA clusters wrapped in setprio (T5).
// All K/V fragment loads are NON-TEMPORAL (nt): skip L1 allocation, stream from L2.
static __device__ __forceinline__ void flash_step(
    const unsigned short* __restrict__ kfl, const unsigned short* __restrict__ vfl,
    int Tn,
    const half8 (&ck)[4], half8 (&nk)[4], half8 (&vA)[4],
    const half8 (&qh)[2][2], const half8 (&ql)[2][2],
    f32x4 (&acc)[2][4], float (&mrow)[2], float (&lrow)[2])
{
    // prefetch next tile's K frags -- contiguous 1KB per instr, imm offsets
    const unsigned short* kn = kfl + (size_t)Tn * 2048;
    #pragma unroll
    for (int f = 0; f < 4; f++) nk[f] = ntload8(kn + f * 512);

    // S tiles (log2-scaled); key of S-frag lane(Q,c) reg r = T*32 + 8Q + 4t + r
    f32x4 S[2][2];   // [t][qt]
    __builtin_amdgcn_s_setprio(1);
    #pragma unroll
    for (int t = 0; t < 2; t++)
        #pragma unroll
        for (int qt = 0; qt < 2; qt++) {
            f32x4 s = MFMA16(ck[2 * t],     qh[qt][0], zero4());
            s = MFMA16(ck[2 * t + 1], qh[qt][1], s);
            s = MFMA16(ck[2 * t],     ql[qt][0], s);
            s = MFMA16(ck[2 * t + 1], ql[qt][1], s);
            S[t][qt] = s;
        }
    __builtin_amdgcn_s_setprio(0);

    float pmax[2];
    #pragma unroll
    for (int qt = 0; qt < 2; qt++) {
        pmax[qt] = fmaxf(fmaxf(fmaxf(S[0][qt][0], S[0][qt][1]),
                               fmaxf(S[0][qt][2], S[0][qt][3])),
                         fmaxf(fmaxf(S[1][qt][0], S[1][qt][1]),
                               fmaxf(S[1][qt][2], S[1][qt][3])));
    }
    // defer-max (T13): wave-uniform gate via __any (VOPC+exec, zero DS ops)
    if (__any((pmax[0] > mrow[0] + GATE_THR) | (pmax[1] > mrow[1] + GATE_THR))) {
        #pragma unroll
        for (int qt = 0; qt < 2; qt++) {
            float cm = pmax[qt];
            cm = fmaxf(cm, __shfl_xor(cm, 16));
            cm = fmaxf(cm, __shfl_xor(cm, 32));   // uniform per q-row c across quads
            const float mn = fmaxf(mrow[qt], cm);
            const float sc = __builtin_amdgcn_exp2f(mrow[qt] - mn);
            mrow[qt] = mn;
            lrow[qt] *= sc;
            #pragma unroll
            for (int dt = 0; dt < 4; dt++)
                #pragma unroll
                for (int r = 0; r < 4; r++) acc[qt][dt][r] *= sc;
        }
    }
    union { half8 v; fp16x2 h2[4]; } pk[2];
    #pragma unroll
    for (int qt = 0; qt < 2; qt++) {
        const float mref = mrow[qt];
        float p[8];
        #pragma unroll
        for (int r = 0; r < 4; r++) {
            p[r]     = __builtin_amdgcn_exp2f(S[0][qt][r] - mref);
            p[4 + r] = __builtin_amdgcn_exp2f(S[1][qt][r] - mref);
        }
        // tree sum (depth 3, not a serial 8-chain); per-lane PARTIAL, reduced in epilogue
        lrow[qt] += ((p[0] + p[1]) + (p[2] + p[3])) + ((p[4] + p[5]) + (p[6] + p[7]));
        // pack pairs f32->fp16 in one v_cvt_pkrtz each; order matches PV B-frag
        #pragma unroll
        for (int j = 0; j < 4; j++)
            pk[qt].h2[j] = __builtin_amdgcn_cvt_pkrtz(p[2 * j], p[2 * j + 1]);
    }
    __builtin_amdgcn_s_setprio(1);
    #pragma unroll
    for (int dt = 0; dt < 4; dt++) {
        acc[0][dt] = MFMA16(vA[dt], pk[0].v, acc[0][dt]);
        acc[1][dt] = MFMA16(vA[dt], pk[1].v, acc[1][dt]);
    }
    __builtin_amdgcn_s_setprio(0);
    // reload vA in-place from next tile (WAR after PV issue; ~3/4-step latency budget)
    const unsigned short* vn = vfl + (size_t)Tn * 2048;
    #pragma unroll
    for (int d = 0; d < 4; d++) vA[d] = ntload8(vn + d * 512);
}

// ---------------- main: 1-wave blocks, 32 rows/wave, barrier-free, frag-major K/V ----------------
__global__ __launch_bounds__(64, 3)
void attn_kernel(const float* __restrict__ x,
                 const unsigned short* __restrict__ GFh,
                 const unsigned short* __restrict__ GFl,
                 const float* __restrict__ uW,
                 const unsigned short* __restrict__ KF,
                 const unsigned short* __restrict__ VF,
                 const float* __restrict__ Wv,
                 const float* __restrict__ bv,
                 float* __restrict__ out)
{
    __shared__ __align__(16) float slice[1088];   // [16][68] f32 Q-transpose slice (wave-private)
    const int lane = threadIdx.x & 63;
    const int Q    = lane >> 4;    // quad 0..3
    const int c    = lane & 15;    // col 0..15
    const int rbase = blockIdx.x * 32;   // this wave's 32 q-rows (3125*32 = 100000 exactly)

    // ------- setup: Q~^T = G^T x^T via MFMA (frag-major G from L2, CACHED) -> q-frags hi/lo -------
    // log2(e) folded into Q~ before the hi/lo split -> scores come out log2-scaled.
    half8 qh[2][2], ql[2][2];   // [rt][ks] -- static indices ONLY
    #pragma unroll
    for (int rt = 0; rt < 2; rt++) {
        const int row = rbase + rt * 16 + c;   // always < N_ROWS (exact tiling)
        half8 xh[2], xl[2];
        #pragma unroll
        for (int ks = 0; ks < 2; ks++) {
            const float* xp = x + (size_t)row * 64 + ks * 32 + Q * 8;
            float a[8];
            *(float4*)a       = *(const float4*)xp;
            *(float4*)(a + 4) = *(const float4*)(xp + 4);
            #pragma unroll
            for (int i = 0; i < 8; i++) {
                _Float16 h = (_Float16)a[i];
                xh[ks][i] = h;
                xl[ks][i] = (_Float16)(a[i] - (float)h);
            }
        }
        #pragma unroll
        for (int mt = 0; mt < 4; mt++) {
            f32x4 Cm = zero4();
            #pragma unroll
            for (int ks = 0; ks < 2; ks++) {
                half8 gh = *(const half8*)(GFh + ((mt * 2 + ks) * 64 + lane) * 8);
                half8 gl = *(const half8*)(GFl + ((mt * 2 + ks) * 64 + lane) * 8);
                Cm = MFMA16(gh, xh[ks], Cm);   // D[dout][x-row]
                Cm = MFMA16(gh, xl[ks], Cm);
                Cm = MFMA16(gl, xh[ks], Cm);
            }
            // C row = dout mt*16+4Q+r, col = x-row c -> slice[x-row][dout]
            *(f32x4*)(slice + c * 68 + mt * 16 + 4 * Q) = Cm;
        }
        __builtin_amdgcn_s_waitcnt(0);   // wave-local LDS RAW (slice is wave-private)
        #pragma unroll
        for (int ks = 0; ks < 2; ks++) {
            const float* qp = slice + c * 68 + ks * 32 + Q * 8;
            const float* up = uW + ks * 32 + Q * 8;
            #pragma unroll
            for (int i = 0; i < 8; i++) {
                float val = (qp[i] + up[i]) * LOG2E;
                _Float16 h = (_Float16)val;
                qh[rt][ks][i] = h;
                ql[rt][ks][i] = (_Float16)(val - (float)h);
            }
        }
        __builtin_amdgcn_s_waitcnt(0);   // reads done before rt=1 overwrites slice
    }

    // ---------------- flash loop: 32 tiles of 32 keys, K dbuf + V in-place prefetch ----------------
    f32x4 acc[2][4];   // [qt][dt] agg^T C-frags (static idx only)
    #pragma unroll
    for (int qt = 0; qt < 2; qt++)
        #pragma unroll
        for (int dt = 0; dt < 4; dt++) acc[qt][dt] = zero4();
    float mrow[2] = { -3.0e38f, -3.0e38f };
    float lrow[2] = { 0.f, 0.f };

    const unsigned short* kfl = KF + lane * 8;   // per-lane frag base (ushort units)
    const unsigned short* vfl = VF + lane * 8;
    half8 kA[4], kB[4], vA[4];
    #pragma unroll
    for (int f = 0; f < 4; f++) kA[f] = ntload8(kfl + f * 512);   // tile 0 K
    #pragma unroll
    for (int d = 0; d < 4; d++) vA[d] = ntload8(vfl + d * 512);   // tile 0 V

    #pragma unroll 1
    for (int TT = 0; TT < 16; TT++) {
        flash_step(kfl, vfl, 2 * TT + 1, kA, kB, vA, qh, ql, acc, mrow, lrow);
        const int Tn = (2 * TT + 2 < 32) ? 2 * TT + 2 : 31;   // clamp last prefetch
        flash_step(kfl, vfl, Tn,         kB, kA, vA, qh, ql, acc, mrow, lrow);
    }

    // ---------------- epilogue: reduce lrow partials, out = (agg/l) @ Wv^T + bv ----------------
    #pragma unroll
    for (int qt = 0; qt < 2; qt++) {
        float l = lrow[qt];
        l += __shfl_xor(l, 16);
        l += __shfl_xor(l, 32);     // once per kernel, not per iter
        const float rl = 1.f / l;
        #pragma unroll
        for (int dt = 0; dt < 4; dt++)
            #pragma unroll
            for (int r = 0; r < 4; r++) acc[qt][dt][r] *= rl;
    }
    half8 wf[4][2];
    #pragma unroll
    for (int mt = 0; mt < 4; mt++)
        #pragma unroll
        for (int ks = 0; ks < 2; ks++) {
            const float* wp = Wv + (size_t)(mt * 16 + c) * 64 + ks * 32 + Q * 8;
            #pragma unroll
            for (int i = 0; i < 8; i++) wf[mt][ks][i] = (_Float16)wp[i];
        }
    const int srcA = 32 * (Q & 1) + c;
    const int srcB = srcA + 16;
    const bool hi = (Q >> 1) & 1;
    f32x4 o[2][4];
    #pragma unroll
    for (int qt = 0; qt < 2; qt++) {
        half8 pe[2];
        #pragma unroll
        for (int ks = 0; ks < 2; ks++) {
            #pragma unroll
            for (int r = 0; r < 4; r++) {
                float a0 = __shfl(acc[qt][2 * ks + 0][r], srcA);
                float a1 = __shfl(acc[qt][2 * ks + 1][r], srcA);
                float b0 = __shfl(acc[qt][2 * ks + 0][r], srcB);
                float b1 = __shfl(acc[qt][2 * ks + 1][r], srcB);
                pe[ks][r]     = (_Float16)(hi ? a1 : a0);
                pe[ks][4 + r] = (_Float16)(hi ? b1 : b0);
            }
        }
        #pragma unroll
        for (int mt = 0; mt < 4; mt++) {
            f32x4 t = MFMA16(wf[mt][0], pe[0], zero4());
            o[qt][mt] = MFMA16(wf[mt][1], pe[1], t);
        }
    }
    #pragma unroll
    for (int qt = 0; qt < 2; qt++) {
        const int row = rbase + qt * 16 + c;   // always < N_ROWS (exact tiling)
        #pragma unroll
        for (int mt = 0; mt < 4; mt++) {
            const float4 bf = *(const float4*)(bv + mt * 16 + 4 * Q);
            float4 vv = make_float4(o[qt][mt][0] + bf.x, o[qt][mt][1] + bf.y,
                                    o[qt][mt][2] + bf.z, o[qt][mt][3] + bf.w);
            *(float4*)(out + (size_t)row * 64 + mt * 16 + 4 * Q) = vv;
        }
    }
}

extern "C" void kernel_launch(void* const* d_in, const int* in_sizes, int n_in,
                              void* d_out, int out_size, void* d_ws, size_t ws_size,
                              hipStream_t stream)
{
    const float* x  = (const float*)d_in[0];
    const float* nb = (const float*)d_in[1];
    const float* Wq = (const float*)d_in[2];
    const float* bq = (const float*)d_in[3];
    const float* Wk = (const float*)d_in[4];
    // d_in[5] = bk: provably cancels in softmax -> unused
    const float* Wv = (const float*)d_in[6];
    const float* bv = (const float*)d_in[7];
    float* out = (float*)d_out;

    char* ws = (char*)d_ws;                                  // needs 278784 B
    unsigned short* GFh = (unsigned short*)(ws);             // 8192 B
    unsigned short* GFl = (unsigned short*)(ws + 8192);      // 8192 B
    float*          uW  = (float*)(ws + 16384);              // 256 B
    unsigned short* KF  = (unsigned short*)(ws + 16640);     // 131072 B
    unsigned short* VF  = (unsigned short*)(ws + 147712);    // 131072 B (end 278784)

    prep_kernel<<<33, 256, 0, stream>>>(nb, Wq, bq, Wk, GFh, GFl, uW, KF, VF);
    const int grid = N_ROWS / 32;   // 3125 1-wave blocks, 32 rows each, zero padding
    attn_kernel<<<grid, 64, 0, stream>>>(x, GFh, GFl, uW, KF, VF, Wv, bv, out);
}

// Round 14
// 149.189 us; speedup vs baseline: 1.0889x; 1.0889x over previous
//
#include <hip/hip_runtime.h>

// RelationGAT fused flash-attention, MFMA fp16 (gfx950) -- FINAL = R16/R18 (best measured, 74.2us attn).
// out = softmax((x@Wq^T+bq) @ (nb@Wk^T+bk)^T) @ nb @ Wv^T + bv
// bk cancels in softmax. Q~ = x@G + u, G = Wq^T Wk, u = bq^T Wk; K=V=raw nb.
//
// FINAL. Session: 199.0 -> 146.7us total (attn 132.7 -> 74.2us, -26% e2e).
// Wins: drop per-block LDS staging of L2-resident K/V (-27%); fragment-major
// pre-formatted K/V layouts -> every loop load one contiguous 1KB wave-block
// (-14%); exp2-domain softmax + defer-max gate + cvt_pkrtz + tree-sum (small).
// Nulls/regressions (13 variants): TLP x2 w/ traffic x2 (+19%), key-split TLP
// x2 at CONSTANT traffic (+10%), ILP x2 (null), cross-step T15 pipeline
// (null), LDS-shared DMA staging (+17%), loads-per-work /2 (null), setprio
// (~0), non-temporal K/V loads (+13%, FETCH 13.7->16.1MB: L1 WAS absorbing
// stream re-reads -- nt pushed them to HBM).
// Plateau: per-step serial service equilibrium at fixed wave concurrency;
// all PMC-visible pipes <40%, HBM <7%; limiting resource not attributable
// from SQ/TCC counters. ~530 TF = 27% of fp16 ubench ceiling, consistent
// with MfmaUtil 23%. Known path past this is the co-designed 8-wave 32x32
// LDS-resident stack -- components measured null when grafted individually.
//
// Workspace layout (278784 B):
//   [0,8192)         GFh  fp16 frag-major G^T hi: [f=mt*2+ks][lane][8]
//   [8192,16384)     GFl  fp16 frag-major G^T lo
//   [16384,16640)    uW   f32 [64]
//   [16640,147712)   KF   fp16 [tile][f=t*2+h][lane][8], key-permuted
//   [147712,278784)  VF   fp16 [tile][dt][lane][8], natural key order

#define N_ROWS 100000
#define LOG2E 1.44269504088896f
#define GATE_THR 11.5424f   // 8 nats in log2 units; p <= 2^11.54 ~ 2981 fits fp16

typedef __attribute__((ext_vector_type(8))) _Float16 half8;
typedef __attribute__((ext_vector_type(2))) __fp16   fp16x2;   // cvt_pkrtz return type
typedef __attribute__((ext_vector_type(4))) float    f32x4;

#define MFMA16(a,b,c) __builtin_amdgcn_mfma_f32_16x16x32_f16((a),(b),(c),0,0,0)

static __device__ __forceinline__ f32x4 zero4() {
    f32x4 v = {0.f, 0.f, 0.f, 0.f};
    return v;
}

// ---------------- prep: GF hi/lo + u (block 0), nb -> KF/VF fp16 (blocks 1..32) ----------------
__global__ __launch_bounds__(256)
void prep_kernel(const float* __restrict__ nb, const float* __restrict__ Wq,
                 const float* __restrict__ bq, const float* __restrict__ Wk,
                 unsigned short* __restrict__ GFh, unsigned short* __restrict__ GFl,
                 float* __restrict__ uW, unsigned short* __restrict__ KF,
                 unsigned short* __restrict__ VF)
{
    __shared__ __align__(16) float sm[8192];   // 32KB: blk0 Wk|Wq, blks>0 transpose tile
    const int tid = threadIdx.x;
    if (blockIdx.x == 0) {
        const float4* wk4 = (const float4*)Wk;
        const float4* wq4 = (const float4*)Wq;
        float4* dk = (float4*)sm;
        float4* dq = (float4*)(sm + 4096);
        #pragma unroll
        for (int u = 0; u < 4; u++) {
            dk[u * 256 + tid] = wk4[u * 256 + tid];
            dq[u * 256 + tid] = wq4[u * 256 + tid];
        }
        __syncthreads();
        const int e2 = tid & 63, e1g = (tid >> 6) * 16;
        float g[16];
        #pragma unroll
        for (int q = 0; q < 16; q++) g[q] = 0.f;
        for (int w = 0; w < 64; w++) {
            float kv = sm[w * 64 + e2];
            const float* wqp = sm + 4096 + w * 64 + e1g;
            #pragma unroll
            for (int q = 0; q < 16; q++) g[q] = fmaf(wqp[q], kv, g[q]);
        }
        union { half8 h; uint4 u; } ph0, pl0, ph1, pl1;
        #pragma unroll
        for (int i = 0; i < 8; i++) {
            _Float16 h0 = (_Float16)g[i];
            ph0.h[i] = h0; pl0.h[i] = (_Float16)(g[i] - (float)h0);
            _Float16 h1 = (_Float16)g[8 + i];
            ph1.h[i] = h1; pl1.h[i] = (_Float16)(g[8 + i] - (float)h1);
        }
        // frag-major: f = mt*2+ks, lane = Q*16+c ; this thread owns row e2 ->
        // (mt = e2>>4, c = e2&15), cols e1g..e1g+15 -> ks = tid>>7, Q0 = 2*((tid>>6)&1)
        const int mt = e2 >> 4, cc = e2 & 15;
        const int ks = tid >> 7, Q0 = 2 * ((tid >> 6) & 1);
        const int f  = mt * 2 + ks;
        *(uint4*)(GFh + (f * 64 + Q0 * 16 + cc) * 8)       = ph0.u;
        *(uint4*)(GFh + (f * 64 + (Q0 + 1) * 16 + cc) * 8) = ph1.u;
        *(uint4*)(GFl + (f * 64 + Q0 * 16 + cc) * 8)       = pl0.u;
        *(uint4*)(GFl + (f * 64 + (Q0 + 1) * 16 + cc) * 8) = pl1.u;
        if (tid < 64) {
            float uu = 0.f;
            for (int w = 0; w < 64; w++) uu = fmaf(bq[w], sm[w * 64 + tid], uu);
            uW[tid] = uu;
        }
    } else {
        const int T0 = blockIdx.x - 1;   // this block's 32-key tile
        const int j0 = T0 * 32;
        // stage 32x64 f32 tile to LDS [32][65] for the VF transpose
        {
            const int jr = tid >> 3, c0 = (tid & 7) * 8;
            const float* np = nb + (size_t)(j0 + jr) * 64 + c0;
            float4 v0 = *(const float4*)np;
            float4 v1 = *(const float4*)(np + 4);
            sm[jr * 65 + c0 + 0] = v0.x; sm[jr * 65 + c0 + 1] = v0.y;
            sm[jr * 65 + c0 + 2] = v0.z; sm[jr * 65 + c0 + 3] = v0.w;
            sm[jr * 65 + c0 + 4] = v1.x; sm[jr * 65 + c0 + 5] = v1.y;
            sm[jr * 65 + c0 + 6] = v1.z; sm[jr * 65 + c0 + 7] = v1.w;
        }
        // KF direct from global: tid -> (f=(t,h), lane=(Q,c)); stored key row is the
        // PERMUTED key keyof(t,c) so that S-frag reg r at lane(Q,c) = key 8Q+4t+r.
        {
            const int f = tid >> 6, ln = tid & 63;
            const int t = f >> 1, h = f & 1, Qw = ln >> 4, cw = ln & 15;
            const int key = ((cw >> 3) & 1) * 16 + ((cw >> 2) & 1) * 8 + 4 * t + (cw & 3);
            const float* kp = nb + (size_t)(j0 + key) * 64 + h * 32 + Qw * 8;
            float b[8];
            *(float4*)b       = *(const float4*)kp;
            *(float4*)(b + 4) = *(const float4*)(kp + 4);
            union { half8 hh; uint4 u; } pk;
            #pragma unroll
            for (int i = 0; i < 8; i++) pk.hh[i] = (_Float16)b[i];
            *(uint4*)(KF + (size_t)T0 * 2048 + f * 512 + ln * 8) = pk.u;
        }
        __syncthreads();
        // VF from LDS transpose: VF[T0][dt][lane(Q,c)][i] = nb[j0 + Q*8 + i][dt*16+c]
        {
            const int dt = tid >> 6, ln = tid & 63;
            const int Qw = ln >> 4, cw = ln & 15;
            union { half8 hh; uint4 u; } pv;
            #pragma unroll
            for (int i = 0; i < 8; i++)
                pv.hh[i] = (_Float16)sm[(Qw * 8 + i) * 65 + dt * 16 + cw];
            *(uint4*)(VF + (size_t)T0 * 2048 + dt * 512 + ln * 8) = pv.u;
        }
    }
}

// One 32-key flash step: compute with ck/vA, prefetch K[Tn] into nk, reload vA <- V[Tn]
// at the end (WAR after PV issue; ~3/4-step slack). MFMA clusters wrapped in setprio (T5).
static __device__ __forceinline__ void flash_step(
    const unsigned short* __restrict__ kfl, const unsigned short* __restrict__ vfl,
    int Tn,
    const half8 (&ck)[4], half8 (&nk)[4], half8 (&vA)[4],
    const half8 (&qh)[2][2], const half8 (&ql)[2][2],
    f32x4 (&acc)[2][4], float (&mrow)[2], float (&lrow)[2])
{
    // prefetch next tile's K frags -- contiguous 1KB per instr, imm offsets
    const unsigned short* kn = kfl + (size_t)Tn * 2048;
    #pragma unroll
    for (int f = 0; f < 4; f++) nk[f] = *(const half8*)(kn + f * 512);

    // S tiles (log2-scaled); key of S-frag lane(Q,c) reg r = T*32 + 8Q + 4t + r
    f32x4 S[2][2];   // [t][qt]
    __builtin_amdgcn_s_setprio(1);
    #pragma unroll
    for (int t = 0; t < 2; t++)
        #pragma unroll
        for (int qt = 0; qt < 2; qt++) {
            f32x4 s = MFMA16(ck[2 * t],     qh[qt][0], zero4());
            s = MFMA16(ck[2 * t + 1], qh[qt][1], s);
            s = MFMA16(ck[2 * t],     ql[qt][0], s);
            s = MFMA16(ck[2 * t + 1], ql[qt][1], s);
            S[t][qt] = s;
        }
    __builtin_amdgcn_s_setprio(0);

    float pmax[2];
    #pragma unroll
    for (int qt = 0; qt < 2; qt++) {
        pmax[qt] = fmaxf(fmaxf(fmaxf(S[0][qt][0], S[0][qt][1]),
                               fmaxf(S[0][qt][2], S[0][qt][3])),
                         fmaxf(fmaxf(S[1][qt][0], S[1][qt][1]),
                               fmaxf(S[1][qt][2], S[1][qt][3])));
    }
    // defer-max (T13): wave-uniform gate via __any (VOPC+exec, zero DS ops)
    if (__any((pmax[0] > mrow[0] + GATE_THR) | (pmax[1] > mrow[1] + GATE_THR))) {
        #pragma unroll
        for (int qt = 0; qt < 2; qt++) {
            float cm = pmax[qt];
            cm = fmaxf(cm, __shfl_xor(cm, 16));
            cm = fmaxf(cm, __shfl_xor(cm, 32));   // uniform per q-row c across quads
            const float mn = fmaxf(mrow[qt], cm);
            const float sc = __builtin_amdgcn_exp2f(mrow[qt] - mn);
            mrow[qt] = mn;
            lrow[qt] *= sc;
            #pragma unroll
            for (int dt = 0; dt < 4; dt++)
                #pragma unroll
                for (int r = 0; r < 4; r++) acc[qt][dt][r] *= sc;
        }
    }
    union { half8 v; fp16x2 h2[4]; } pk[2];
    #pragma unroll
    for (int qt = 0; qt < 2; qt++) {
        const float mref = mrow[qt];
        float p[8];
        #pragma unroll
        for (int r = 0; r < 4; r++) {
            p[r]     = __builtin_amdgcn_exp2f(S[0][qt][r] - mref);
            p[4 + r] = __builtin_amdgcn_exp2f(S[1][qt][r] - mref);
        }
        // tree sum (depth 3, not a serial 8-chain); per-lane PARTIAL, reduced in epilogue
        lrow[qt] += ((p[0] + p[1]) + (p[2] + p[3])) + ((p[4] + p[5]) + (p[6] + p[7]));
        // pack pairs f32->fp16 in one v_cvt_pkrtz each; order matches PV B-frag
        #pragma unroll
        for (int j = 0; j < 4; j++)
            pk[qt].h2[j] = __builtin_amdgcn_cvt_pkrtz(p[2 * j], p[2 * j + 1]);
    }
    __builtin_amdgcn_s_setprio(1);
    #pragma unroll
    for (int dt = 0; dt < 4; dt++) {
        acc[0][dt] = MFMA16(vA[dt], pk[0].v, acc[0][dt]);
        acc[1][dt] = MFMA16(vA[dt], pk[1].v, acc[1][dt]);
    }
    __builtin_amdgcn_s_setprio(0);
    // reload vA in-place from next tile (WAR after PV issue; ~3/4-step latency budget)
    const unsigned short* vn = vfl + (size_t)Tn * 2048;
    #pragma unroll
    for (int d = 0; d < 4; d++) vA[d] = *(const half8*)(vn + d * 512);
}

// ---------------- main: 1-wave blocks, 32 rows/wave, barrier-free, frag-major K/V ----------------
__global__ __launch_bounds__(64, 3)
void attn_kernel(const float* __restrict__ x,
                 const unsigned short* __restrict__ GFh,
                 const unsigned short* __restrict__ GFl,
                 const float* __restrict__ uW,
                 const unsigned short* __restrict__ KF,
                 const unsigned short* __restrict__ VF,
                 const float* __restrict__ Wv,
                 const float* __restrict__ bv,
                 float* __restrict__ out)
{
    __shared__ __align__(16) float slice[1088];   // [16][68] f32 Q-transpose slice (wave-private)
    const int lane = threadIdx.x & 63;
    const int Q    = lane >> 4;    // quad 0..3
    const int c    = lane & 15;    // col 0..15
    const int rbase = blockIdx.x * 32;   // this wave's 32 q-rows (3125*32 = 100000 exactly)

    // ------- setup: Q~^T = G^T x^T via MFMA (frag-major G from L2) -> q-frags hi/lo -------
    // log2(e) folded into Q~ before the hi/lo split -> scores come out log2-scaled.
    half8 qh[2][2], ql[2][2];   // [rt][ks] -- static indices ONLY
    #pragma unroll
    for (int rt = 0; rt < 2; rt++) {
        const int row = rbase + rt * 16 + c;   // always < N_ROWS (exact tiling)
        half8 xh[2], xl[2];
        #pragma unroll
        for (int ks = 0; ks < 2; ks++) {
            const float* xp = x + (size_t)row * 64 + ks * 32 + Q * 8;
            float a[8];
            *(float4*)a       = *(const float4*)xp;
            *(float4*)(a + 4) = *(const float4*)(xp + 4);
            #pragma unroll
            for (int i = 0; i < 8; i++) {
                _Float16 h = (_Float16)a[i];
                xh[ks][i] = h;
                xl[ks][i] = (_Float16)(a[i] - (float)h);
            }
        }
        #pragma unroll
        for (int mt = 0; mt < 4; mt++) {
            f32x4 Cm = zero4();
            #pragma unroll
            for (int ks = 0; ks < 2; ks++) {
                half8 gh = *(const half8*)(GFh + ((mt * 2 + ks) * 64 + lane) * 8);
                half8 gl = *(const half8*)(GFl + ((mt * 2 + ks) * 64 + lane) * 8);
                Cm = MFMA16(gh, xh[ks], Cm);   // D[dout][x-row]
                Cm = MFMA16(gh, xl[ks], Cm);
                Cm = MFMA16(gl, xh[ks], Cm);
            }
            // C row = dout mt*16+4Q+r, col = x-row c -> slice[x-row][dout]
            *(f32x4*)(slice + c * 68 + mt * 16 + 4 * Q) = Cm;
        }
        __builtin_amdgcn_s_waitcnt(0);   // wave-local LDS RAW (slice is wave-private)
        #pragma unroll
        for (int ks = 0; ks < 2; ks++) {
            const float* qp = slice + c * 68 + ks * 32 + Q * 8;
            const float* up = uW + ks * 32 + Q * 8;
            #pragma unroll
            for (int i = 0; i < 8; i++) {
                float val = (qp[i] + up[i]) * LOG2E;
                _Float16 h = (_Float16)val;
                qh[rt][ks][i] = h;
                ql[rt][ks][i] = (_Float16)(val - (float)h);
            }
        }
        __builtin_amdgcn_s_waitcnt(0);   // reads done before rt=1 overwrites slice
    }

    // ---------------- flash loop: 32 tiles of 32 keys, K dbuf + V in-place prefetch ----------------
    f32x4 acc[2][4];   // [qt][dt] agg^T C-frags (static idx only)
    #pragma unroll
    for (int qt = 0; qt < 2; qt++)
        #pragma unroll
        for (int dt = 0; dt < 4; dt++) acc[qt][dt] = zero4();
    float mrow[2] = { -3.0e38f, -3.0e38f };
    float lrow[2] = { 0.f, 0.f };

    const unsigned short* kfl = KF + lane * 8;   // per-lane frag base (ushort units)
    const unsigned short* vfl = VF + lane * 8;
    half8 kA[4], kB[4], vA[4];
    #pragma unroll
    for (int f = 0; f < 4; f++) kA[f] = *(const half8*)(kfl + f * 512);   // tile 0 K
    #pragma unroll
    for (int d = 0; d < 4; d++) vA[d] = *(const half8*)(vfl + d * 512);   // tile 0 V

    #pragma unroll 1
    for (int TT = 0; TT < 16; TT++) {
        flash_step(kfl, vfl, 2 * TT + 1, kA, kB, vA, qh, ql, acc, mrow, lrow);
        const int Tn = (2 * TT + 2 < 32) ? 2 * TT + 2 : 31;   // clamp last prefetch
        flash_step(kfl, vfl, Tn,         kB, kA, vA, qh, ql, acc, mrow, lrow);
    }

    // ---------------- epilogue: reduce lrow partials, out = (agg/l) @ Wv^T + bv ----------------
    #pragma unroll
    for (int qt = 0; qt < 2; qt++) {
        float l = lrow[qt];
        l += __shfl_xor(l, 16);
        l += __shfl_xor(l, 32);     // once per kernel, not per iter
        const float rl = 1.f / l;
        #pragma unroll
        for (int dt = 0; dt < 4; dt++)
            #pragma unroll
            for (int r = 0; r < 4; r++) acc[qt][dt][r] *= rl;
    }
    half8 wf[4][2];
    #pragma unroll
    for (int mt = 0; mt < 4; mt++)
        #pragma unroll
        for (int ks = 0; ks < 2; ks++) {
            const float* wp = Wv + (size_t)(mt * 16 + c) * 64 + ks * 32 + Q * 8;
            #pragma unroll
            for (int i = 0; i < 8; i++) wf[mt][ks][i] = (_Float16)wp[i];
        }
    const int srcA = 32 * (Q & 1) + c;
    const int srcB = srcA + 16;
    const bool hi = (Q >> 1) & 1;
    f32x4 o[2][4];
    #pragma unroll
    for (int qt = 0; qt < 2; qt++) {
        half8 pe[2];
        #pragma unroll
        for (int ks = 0; ks < 2; ks++) {
            #pragma unroll
            for (int r = 0; r < 4; r++) {
                float a0 = __shfl(acc[qt][2 * ks + 0][r], srcA);
                float a1 = __shfl(acc[qt][2 * ks + 1][r], srcA);
                float b0 = __shfl(acc[qt][2 * ks + 0][r], srcB);
                float b1 = __shfl(acc[qt][2 * ks + 1][r], srcB);
                pe[ks][r]     = (_Float16)(hi ? a1 : a0);
                pe[ks][4 + r] = (_Float16)(hi ? b1 : b0);
            }
        }
        #pragma unroll
        for (int mt = 0; mt < 4; mt++) {
            f32x4 t = MFMA16(wf[mt][0], pe[0], zero4());
            o[qt][mt] = MFMA16(wf[mt][1], pe[1], t);
        }
    }
    #pragma unroll
    for (int qt = 0; qt < 2; qt++) {
        const int row = rbase + qt * 16 + c;   // always < N_ROWS (exact tiling)
        #pragma unroll
        for (int mt = 0; mt < 4; mt++) {
            const float4 bf = *(const float4*)(bv + mt * 16 + 4 * Q);
            float4 vv = make_float4(o[qt][mt][0] + bf.x, o[qt][mt][1] + bf.y,
                                    o[qt][mt][2] + bf.z, o[qt][mt][3] + bf.w);
            *(float4*)(out + (size_t)row * 64 + mt * 16 + 4 * Q) = vv;
        }
    }
}

extern "C" void kernel_launch(void* const* d_in, const int* in_sizes, int n_in,
                              void* d_out, int out_size, void* d_ws, size_t ws_size,
                              hipStream_t stream)
{
    const float* x  = (const float*)d_in[0];
    const float* nb = (const float*)d_in[1];
    const float* Wq = (const float*)d_in[2];
    const float* bq = (const float*)d_in[3];
    const float* Wk = (const float*)d_in[4];
    // d_in[5] = bk: provably cancels in softmax -> unused
    const float* Wv = (const float*)d_in[6];
    const float* bv = (const float*)d_in[7];
    float* out = (float*)d_out;

    char* ws = (char*)d_ws;                                  // needs 278784 B
    unsigned short* GFh = (unsigned short*)(ws);             // 8192 B
    unsigned short* GFl = (unsigned short*)(ws + 8192);      // 8192 B
    float*          uW  = (float*)(ws + 16384);              // 256 B
    unsigned short* KF  = (unsigned short*)(ws + 16640);     // 131072 B
    unsigned short* VF  = (unsigned short*)(ws + 147712);    // 131072 B (end 278784)

    prep_kernel<<<33, 256, 0, stream>>>(nb, Wq, bq, Wk, GFh, GFl, uW, KF, VF);
    const int grid = N_ROWS / 32;   // 3125 1-wave blocks, 32 rows each, zero padding
    attn_kernel<<<grid, 64, 0, stream>>>(x, GFh, GFl, uW, KF, VF, Wv, bv, out);
}